// Round 14
// baseline (385.647 us; speedup 1.0000x reference)
//
#include <hip/hip_runtime.h>
#include <cstdint>
#include <cstddef>

#define DEV __device__ __forceinline__

typedef __bf16 bf16x8 __attribute__((ext_vector_type(8)));
typedef float f32x4 __attribute__((ext_vector_type(4)));

DEV unsigned short f2bf(float f) {
  unsigned u = __builtin_bit_cast(unsigned, f);
  u += 0x7fffu + ((u >> 16) & 1u);   // RNE
  return (unsigned short)(u >> 16);
}
DEV float bf2f(unsigned short h) {
  return __builtin_bit_cast(float, (unsigned)h << 16);
}

// =====================================================================================
// Fused prep: concat [x|event]->Aaug[8192x1152]  +  5 weight transposes.
// =====================================================================================
__global__ __launch_bounds__(256)
void k_prep(const float* __restrict__ x, const float* __restrict__ ev,
            unsigned short* __restrict__ Aaug,
            const float* __restrict__ W_in, unsigned short* __restrict__ WinT,
            const float* __restrict__ ipW, unsigned short* __restrict__ ipT,
            const float* __restrict__ xpW, unsigned short* __restrict__ xpT,
            const float* __restrict__ dpW, unsigned short* __restrict__ dpT,
            const float* __restrict__ opW, unsigned short* __restrict__ opT) {
  int tid = threadIdx.x;
  int idx = blockIdx.x;
  // R0: concat, 16384 blocks
  if (idx < 16384) {
    int col4 = (idx & 1) * 256 + tid;
    if (col4 >= 288) return;
    size_t row = idx >> 1;
    float4 v = make_float4(0.f, 0.f, 0.f, 0.f);
    if (col4 < 256)      v = reinterpret_cast<const float4*>(x + row * 1024)[col4];
    else if (col4 < 272) v = reinterpret_cast<const float4*>(ev + row * 64)[col4 - 256];
    ushort4 o; o.x = f2bf(v.x); o.y = f2bf(v.y); o.z = f2bf(v.z); o.w = f2bf(v.w);
    reinterpret_cast<ushort4*>(Aaug + row * 1152)[col4] = o;
    return;
  }
  idx -= 16384;
  const float* in; unsigned short* out; int R, C, Rout, Cout, gx;
  if (idx < 1152)      { in = W_in; out = WinT; R = 1088; C = 1024; Rout = 1152; Cout = 1024; gx = 32; }
  else if ((idx -= 1152) < 4096) { in = ipW; out = ipT; R = 1024; C = 4096; Rout = 1024; Cout = 4096; gx = 128; }
  else if ((idx -= 4096) < 256)  { in = xpW; out = xpT; R = 2048; C = 96;   Rout = 2048; Cout = 128;  gx = 4;   }
  else if ((idx -= 256) < 128)   { in = dpW; out = dpT; R = 64;   C = 2048; Rout = 64;   Cout = 2048; gx = 64;  }
  else                 { idx -= 128; in = opW; out = opT; R = 2048; C = 1024; Rout = 2048; Cout = 1024; gx = 32; }
  int cx = idx % gx, ry = idx / gx;
  __shared__ float tile[32][33];
  int c0 = cx * 32, r0 = ry * 32;
  int tx = tid & 31, ty = tid >> 5;   // 32 x 8
#pragma unroll
  for (int i = 0; i < 4; ++i) {
    int r = r0 + ty + i * 8, c = c0 + tx;
    tile[ty + i * 8][tx] = (r < R && c < C) ? in[(size_t)r * C + c] : 0.f;
  }
  __syncthreads();
#pragma unroll
  for (int i = 0; i < 4; ++i) {
    int c = c0 + ty + i * 8, r = r0 + tx;
    if (c < Cout && r < Rout) out[(size_t)c * Rout + r] = f2bf(tile[tx][ty + i * 8]);
  }
}

// =====================================================================================
// 4-WINDOW 256xBN MFMA GEMM (r8 schedule, frozen) — aug (EPI 0) and out_proj (EPI 4).
// =====================================================================================
template <int BN, int EPI>
__global__ __launch_bounds__(512, 1)
void k_gemm8(const unsigned short* __restrict__ A, const unsigned short* __restrict__ Bt,
             int N, int NT, int lda, int ldb,
             float* __restrict__ outF, unsigned short* __restrict__ outB1,
             unsigned short* __restrict__ outB2,
             const float* __restrict__ bias, const unsigned short* __restrict__ residB) {
  static_assert(BN == 128 || BN == 256, "");
  constexpr int NF = BN / 64;
  constexpr int NHF = NF / 2;
  constexpr int BLOADS = BN / 128;
  constexpr int ATILE = 256 * 64;
  constexpr int BTILE = BN * 64;
  constexpr int BUFSZ = ATILE + BTILE;
  __shared__ unsigned short lds[2 * BUFSZ];

  const int tid = threadIdx.x;
  const int lane = tid & 63, w = tid >> 6;
  const int wm = w >> 2, wn = w & 3;
  const int frow = lane & 15, fk = lane >> 4;

  const int nbx = gridDim.x;
  const int nwg = nbx * gridDim.y;
  const int orig = blockIdx.y * nbx + blockIdx.x;
  const int swz = (orig & 7) * (nwg >> 3) + (orig >> 3);
  const int brow = swz / nbx, bcol = swz % nbx;
  const size_t row0 = (size_t)brow * 256, col0 = (size_t)bcol * BN;

  f32x4 acc[8][NF];
#pragma unroll
  for (int i = 0; i < 8; ++i)
#pragma unroll
    for (int j = 0; j < NF; ++j) acc[i][j] = f32x4{0.f, 0.f, 0.f, 0.f};

  bf16x8 afr[4][2], bq0[NHF][2], bq1[NHF][2];

  const int srow = tid >> 3;
  const int g8 = ((tid & 7) ^ (srow & 7)) * 8;
  const size_t offA_h0l0 = (row0 + 0 * 128 + 0 * 64 + srow) * (size_t)lda + g8;
  const size_t offA_h0l1 = (row0 + 1 * 128 + 0 * 64 + srow) * (size_t)lda + g8;
  const size_t offA_h1l0 = (row0 + 0 * 128 + 1 * 64 + srow) * (size_t)lda + g8;
  const size_t offA_h1l1 = (row0 + 1 * 128 + 1 * 64 + srow) * (size_t)lda + g8;
  const size_t offB_h0l0 = (col0 + 0 * (BN / 2) + 0 * 64 + srow) * (size_t)ldb + g8;
  const size_t offB_h1l0 = (col0 + 1 * (BN / 2) + 0 * 64 + srow) * (size_t)ldb + g8;
  const size_t offB_h0l1 = (BLOADS == 2) ? ((col0 + 0 * (BN / 2) + 1 * 64 + srow) * (size_t)ldb + g8) : 0;
  const size_t offB_h1l1 = (BLOADS == 2) ? ((col0 + 1 * (BN / 2) + 1 * 64 + srow) * (size_t)ldb + g8) : 0;

  char* ldsb = reinterpret_cast<char*>(lds);
  const int fr7 = frow & 7;
  const int slot0 = (fk ^ fr7) * 16;
  const int slot1 = ((4 + fk) ^ fr7) * 16;
  const int abase0 = (wm * 128 + frow) * 128 + slot0;
  const int abase1 = (wm * 128 + frow) * 128 + slot1;
  const int bbase0 = (wn * (BN / 4) + frow) * 128 + slot0 + ATILE * 2;
  const int bbase1 = (wn * (BN / 4) + frow) * 128 + slot1 + ATILE * 2;

  auto stageA = [&](int p, int tau, int half) {
    const size_t kadd = (size_t)tau * 64;
    const unsigned short* s0 = A + (half ? offA_h1l0 : offA_h0l0) + kadd;
    const unsigned short* s1 = A + (half ? offA_h1l1 : offA_h0l1) + kadd;
    unsigned short* dst = lds + p * BUFSZ + half * 4096 + w * 512;
    __builtin_amdgcn_global_load_lds(s0, dst, 16, 0, 0);
    __builtin_amdgcn_global_load_lds(s1, dst + 8192, 16, 0, 0);
  };
  auto stageB = [&](int p, int tau, int half) {
    const size_t kadd = (size_t)tau * 64;
    unsigned short* dst = lds + p * BUFSZ + ATILE + half * (BTILE / 2) + w * 512;
    const unsigned short* s0 = Bt + (half ? offB_h1l0 : offB_h0l0) + kadd;
    __builtin_amdgcn_global_load_lds(s0, dst, 16, 0, 0);
    if constexpr (BLOADS == 2) {
      const unsigned short* s1 = Bt + (half ? offB_h1l1 : offB_h0l1) + kadd;
      __builtin_amdgcn_global_load_lds(s1, dst + 4096, 16, 0, 0);
    }
  };
  auto ldA = [&](int p, int mh) {
    const int pb = p * (BUFSZ * 2);
#pragma unroll
    for (int mi = 0; mi < 4; ++mi) {
      const int off = pb + (mh * 64 + mi * 16) * 128;
      afr[mi][0] = *reinterpret_cast<const bf16x8*>(ldsb + abase0 + off);
      afr[mi][1] = *reinterpret_cast<const bf16x8*>(ldsb + abase1 + off);
    }
  };
  auto ldB = [&](int p, int nh, bf16x8 (&bq)[NHF][2]) {
    const int pb = p * (BUFSZ * 2);
#pragma unroll
    for (int ni = 0; ni < NHF; ++ni) {
      const int off = pb + (nh * (BN / 8) + ni * 16) * 128;
      bq[ni][0] = *reinterpret_cast<const bf16x8*>(ldsb + bbase0 + off);
      bq[ni][1] = *reinterpret_cast<const bf16x8*>(ldsb + bbase1 + off);
    }
  };

#define MMAQ(MH, NH, BQ)                                                          \
  do {                                                                            \
    _Pragma("unroll") for (int mi = 0; mi < 4; ++mi)                              \
        _Pragma("unroll") for (int ni = 0; ni < NHF; ++ni)                        \
            _Pragma("unroll") for (int kb = 0; kb < 2; ++kb)                      \
                acc[(MH)*4 + mi][(NH)*NHF + ni] =                                 \
                    __builtin_amdgcn_mfma_f32_16x16x32_bf16(                      \
                        afr[mi][kb], BQ[ni][kb], acc[(MH)*4 + mi][(NH)*NHF + ni], \
                        0, 0, 0);                                                 \
  } while (0)

#define PRIO1 __builtin_amdgcn_s_setprio(1)
#define PRIO0 __builtin_amdgcn_s_setprio(0)
#define BARC  __builtin_amdgcn_s_barrier()
#define SBAR  __builtin_amdgcn_sched_barrier(0)
#define VMCNT_WAIT                                                     \
  do {                                                                 \
    if constexpr (BN == 256)                                           \
      asm volatile("s_waitcnt vmcnt(6)" ::: "memory");                 \
    else                                                               \
      asm volatile("s_waitcnt vmcnt(4)" ::: "memory");                 \
  } while (0)

  stageA(0, 0, 0); stageB(0, 0, 0); stageB(0, 0, 1); stageA(0, 0, 1);
  SBAR;
  stageA(1, 1, 0); stageB(1, 1, 0); stageB(1, 1, 1);
  VMCNT_WAIT;
  BARC; SBAR;

  const int niter = NT >> 1;
  for (int it = 0; it < niter; ++it) {
    int t = 2 * it;
    int t1s = t + 1;
    int t2s = (t + 2 < NT) ? t + 2 : NT - 1;
    int t3s = (t + 3 < NT) ? t + 3 : NT - 1;
    // alpha (tile t, buf0)
    ldA(0, 0); ldB(0, 0, bq0); ldB(0, 1, bq1);
    stageA(1, t1s, 1);
    BARC; PRIO1; MMAQ(0, 0, bq0); MMAQ(0, 1, bq1); PRIO0; BARC;
    // beta (tile t, buf0)
    ldA(0, 1);
    stageA(0, t2s, 0); stageB(0, t2s, 0); stageB(0, t2s, 1);
    VMCNT_WAIT;
    BARC; PRIO1; MMAQ(1, 1, bq1); MMAQ(1, 0, bq0); PRIO0; BARC;
    // gamma (tile t+1, buf1)
    ldA(1, 0); ldB(1, 0, bq0); ldB(1, 1, bq1);
    stageA(0, t2s, 1);
    BARC; PRIO1; MMAQ(0, 0, bq0); MMAQ(0, 1, bq1); PRIO0; BARC;
    // delta (tile t+1, buf1)
    ldA(1, 1);
    stageA(1, t3s, 0); stageB(1, t3s, 0); stageB(1, t3s, 1);
    VMCNT_WAIT;
    BARC; PRIO1; MMAQ(1, 1, bq1); MMAQ(1, 0, bq0); PRIO0; BARC;
  }

#pragma unroll
  for (int q = 0; q < 8; ++q) {
#pragma unroll
    for (int j = 0; j < NF; ++j) {
#pragma unroll
      for (int r = 0; r < 4; ++r) {
        size_t row = row0 + wm * 128 + q * 16 + fk * 4 + r;
        size_t col = col0 + wn * (BN / 4) + j * 16 + frow;
        float v = acc[q][j][r];
        if constexpr (EPI == 0) {
          outB1[row * N + col] = f2bf(v + bias[col]);
        } else if constexpr (EPI == 1) {
          int hn = N >> 1;
          if ((int)col < hn) outB1[row * hn + col] = f2bf(v);
          else               outB2[row * hn + (col - hn)] = f2bf(v);
        } else {
          outF[row * N + col] = bf2f(residB[row * N + col]) + v;
        }
      }
    }
  }
#undef MMAQ
#undef PRIO1
#undef PRIO0
#undef BARC
#undef SBAR
#undef VMCNT_WAIT
}

// =====================================================================================
// 2-PHASE 128x128 MFMA GEMM, double-buffered 64KB LDS -> 2 blocks/CU (cross-block
// overlap, m114): per K-tile {stage(nxt); read(cur)+MFMA; vmcnt(0); barrier}.
// Catalog T3-minimum recipe. EPI 1: split halves -> outB1/outB2 bf16 (in_proj).
// =====================================================================================
template <int EPI>
__global__ __launch_bounds__(256)
void k_gemm2(const unsigned short* __restrict__ A, const unsigned short* __restrict__ Bt,
             int N, int K, int lda, int ldb,
             unsigned short* __restrict__ outB1, unsigned short* __restrict__ outB2) {
  __shared__ alignas(16) unsigned short sA[2][128 * 64];
  __shared__ alignas(16) unsigned short sB[2][128 * 64];
  const int tid = threadIdx.x;
  const int lane = tid & 63, w = tid >> 6;
  const int nbx = gridDim.x;
  const int nwg = nbx * gridDim.y;
  const int orig = blockIdx.y * nbx + blockIdx.x;
  const int swz = (orig & 7) * (nwg >> 3) + (orig >> 3);
  const int brow = swz / nbx, bcol = swz % nbx;
  const size_t row0 = (size_t)brow * 128, col0 = (size_t)bcol * 128;

  const int lrow_s = tid >> 3;   // staging row 0..31 (+32 per round)
  const int g_s = tid & 7;
  const int wrow = (w >> 1) * 64, wcol = (w & 1) * 64;
  const int frow = lane & 15, fk = lane >> 4;
  f32x4 acc[4][4] = {};

  auto stage = [&](int p, int kt) {
#pragma unroll
    for (int r = 0; r < 4; ++r) {
      int lr = r * 32 + lrow_s;
      int gs = g_s ^ (lr & 7);
      const unsigned short* srcA = A + (size_t)(row0 + lr) * lda + kt + gs * 8;
      const unsigned short* srcB = Bt + (size_t)(col0 + lr) * ldb + kt + gs * 8;
      unsigned short* dstA = sA[p] + (r * 32 + w * 8) * 64;
      unsigned short* dstB = sB[p] + (r * 32 + w * 8) * 64;
      __builtin_amdgcn_global_load_lds(srcA, dstA, 16, 0, 0);
      __builtin_amdgcn_global_load_lds(srcB, dstB, 16, 0, 0);
    }
  };

  const int NT = K >> 6;
  // prologue: stage tile 0 into buf0, drain fully
  stage(0, 0);
  asm volatile("s_waitcnt vmcnt(0)" ::: "memory");
  __builtin_amdgcn_s_barrier();
  __builtin_amdgcn_sched_barrier(0);

  for (int t = 0; t < NT; ++t) {
    const int cur = t & 1, nxt = cur ^ 1;
    const bool more = (t + 1 < NT);
    if (more) stage(nxt, (t + 1) * 64);      // issue next tile (lands under MFMA)
    __builtin_amdgcn_s_setprio(1);
#pragma unroll
    for (int kw = 0; kw < 2; ++kw) {
      bf16x8 af[4], bfr[4];
      int gk = kw * 4 + fk;
#pragma unroll
      for (int mi = 0; mi < 4; ++mi) {
        int rr = wrow + mi * 16 + frow;
        af[mi] = *reinterpret_cast<const bf16x8*>(sA[cur] + rr * 64 + ((gk ^ (rr & 7)) * 8));
      }
#pragma unroll
      for (int ni = 0; ni < 4; ++ni) {
        int rr = wcol + ni * 16 + frow;
        bfr[ni] = *reinterpret_cast<const bf16x8*>(sB[cur] + rr * 64 + ((gk ^ (rr & 7)) * 8));
      }
#pragma unroll
      for (int mi = 0; mi < 4; ++mi)
#pragma unroll
        for (int ni = 0; ni < 4; ++ni)
          acc[mi][ni] = __builtin_amdgcn_mfma_f32_16x16x32_bf16(af[mi], bfr[ni], acc[mi][ni], 0, 0, 0);
    }
    __builtin_amdgcn_s_setprio(0);
    if (more) {
      asm volatile("s_waitcnt vmcnt(0)" ::: "memory");  // nxt landed
      __builtin_amdgcn_s_barrier();                     // all waves' cur-reads done
      __builtin_amdgcn_sched_barrier(0);                // pin next iter's ds_reads
    }
  }

#pragma unroll
  for (int mi = 0; mi < 4; ++mi) {
#pragma unroll
    for (int ni = 0; ni < 4; ++ni) {
#pragma unroll
      for (int r = 0; r < 4; ++r) {
        size_t row = row0 + wrow + mi * 16 + fk * 4 + r;
        size_t col = col0 + wcol + ni * 16 + frow;
        float v = acc[mi][ni][r];
        if constexpr (EPI == 1) {
          int hn = N >> 1;
          if ((int)col < hn) outB1[row * hn + col] = f2bf(v);
          else               outB2[row * hn + (col - hn)] = f2bf(v);
        }
      }
    }
  }
}

// ---------------- 128x128 MFMA GEMM (m97 structure) for the small GEMMs ----------------
// EPI 3: outB1 = bf16(softplus(acc + bias[col]))  (dt)
// EPI 6: split-K partial: outF[kslice] (fp32, kslice = bcol; col0 forced 0)
template <int EPI>
__global__ __launch_bounds__(256)
void k_gemm(const unsigned short* __restrict__ A, const unsigned short* __restrict__ Bt,
            int N, int K, int lda, int ldb,
            unsigned short* __restrict__ outB1, const float* __restrict__ bias,
            float* __restrict__ outF) {
  __shared__ alignas(16) unsigned short sA[128 * 64];
  __shared__ alignas(16) unsigned short sB[128 * 64];
  int tid = threadIdx.x;
  int lane = tid & 63, w = tid >> 6;
  int nbx = gridDim.x;
  int nwg = nbx * gridDim.y;
  int orig = blockIdx.y * nbx + blockIdx.x;
  int swz = (orig & 7) * (nwg >> 3) + (orig >> 3);
  int brow = swz / nbx, bcol = swz % nbx;
  size_t row0 = (size_t)brow * 128, col0 = (size_t)bcol * 128;
  int ks = 0;
  if constexpr (EPI == 6) { ks = bcol; col0 = 0; }
  const size_t kbase = (size_t)ks * 1024;

  int lrow_s = tid >> 3;
  int g_s = tid & 7;
  int wrow = (w >> 1) * 64, wcol = (w & 1) * 64;
  int frow = lane & 15, fk = lane >> 4;
  f32x4 acc[4][4] = {};

  for (int kt = 0; kt < K; kt += 64) {
    __syncthreads();
#pragma unroll
    for (int r = 0; r < 4; ++r) {
      int lr = r * 32 + lrow_s;
      int gs = g_s ^ (lr & 7);
      const unsigned short* srcA = A + (size_t)(row0 + lr) * lda + kbase + kt + gs * 8;
      const unsigned short* srcB = Bt + (size_t)(col0 + lr) * ldb + kbase + kt + gs * 8;
      unsigned short* dstA = sA + (r * 32 + w * 8) * 64;
      unsigned short* dstB = sB + (r * 32 + w * 8) * 64;
      __builtin_amdgcn_global_load_lds(srcA, dstA, 16, 0, 0);
      __builtin_amdgcn_global_load_lds(srcB, dstB, 16, 0, 0);
    }
    __syncthreads();
#pragma unroll
    for (int kw = 0; kw < 2; ++kw) {
      bf16x8 af[4], bfr[4];
      int gk = kw * 4 + fk;
#pragma unroll
      for (int mi = 0; mi < 4; ++mi) {
        int rr = wrow + mi * 16 + frow;
        af[mi] = *reinterpret_cast<const bf16x8*>(sA + rr * 64 + ((gk ^ (rr & 7)) * 8));
      }
#pragma unroll
      for (int ni = 0; ni < 4; ++ni) {
        int rr = wcol + ni * 16 + frow;
        bfr[ni] = *reinterpret_cast<const bf16x8*>(sB + rr * 64 + ((gk ^ (rr & 7)) * 8));
      }
#pragma unroll
      for (int mi = 0; mi < 4; ++mi)
#pragma unroll
        for (int ni = 0; ni < 4; ++ni)
          acc[mi][ni] = __builtin_amdgcn_mfma_f32_16x16x32_bf16(af[mi], bfr[ni], acc[mi][ni], 0, 0, 0);
    }
  }

#pragma unroll
  for (int mi = 0; mi < 4; ++mi) {
#pragma unroll
    for (int ni = 0; ni < 4; ++ni) {
#pragma unroll
      for (int r = 0; r < 4; ++r) {
        size_t row = row0 + wrow + mi * 16 + fk * 4 + r;
        size_t col = col0 + wcol + ni * 16 + frow;
        float v = acc[mi][ni][r];
        if constexpr (EPI == 6) {
          outF[(size_t)ks * (8192ull * 128) + row * 128 + col] = v;
        } else {
          float xx = v + bias[col];
          float sp = (xx > 15.f) ? xx : __logf(1.f + __expf(xx));
          outB1[row * N + col] = f2bf(sp);
        }
      }
    }
  }
}

// ---------------- combine split-K partials -> bf16 dbl ----------------
__global__ __launch_bounds__(256)
void k_comb(const float* __restrict__ P, unsigned short* __restrict__ dbl) {
  size_t i4 = (size_t)blockIdx.x * 256 + threadIdx.x;   // float4 index, 262144 total
  float4 a = reinterpret_cast<const float4*>(P)[i4];
  float4 b = reinterpret_cast<const float4*>(P + 8192ull * 128)[i4];
  ushort4 o;
  o.x = f2bf(a.x + b.x); o.y = f2bf(a.y + b.y);
  o.z = f2bf(a.z + b.z); o.w = f2bf(a.w + b.w);
  reinterpret_cast<ushort4*>(dbl)[i4] = o;
}

// ---------------- LayerNorm over D=1024, bf16 in -> bf16 out ----------------
__global__ __launch_bounds__(256)
void k_ln(const unsigned short* __restrict__ aug, const float* __restrict__ gam,
          const float* __restrict__ bet, unsigned short* __restrict__ h) {
  int tid = threadIdx.x;
  size_t row = blockIdx.x;
  ushort4 raw = reinterpret_cast<const ushort4*>(aug + row * 1024)[tid];
  float v0 = bf2f(raw.x), v1 = bf2f(raw.y), v2 = bf2f(raw.z), v3 = bf2f(raw.w);
  float s = v0 + v1 + v2 + v3;
  float ss = v0 * v0 + v1 * v1 + v2 * v2 + v3 * v3;
#pragma unroll
  for (int m = 32; m >= 1; m >>= 1) {
    s += __shfl_xor(s, m, 64);
    ss += __shfl_xor(ss, m, 64);
  }
  __shared__ float rb[8];
  if ((tid & 63) == 0) { rb[tid >> 6] = s; rb[4 + (tid >> 6)] = ss; }
  __syncthreads();
  float ts = rb[0] + rb[1] + rb[2] + rb[3];
  float tss = rb[4] + rb[5] + rb[6] + rb[7];
  float mu = ts * (1.f / 1024.f);
  float var = tss * (1.f / 1024.f) - mu * mu;
  float rs = rsqrtf(var + 1e-5f);
  float4 gv = reinterpret_cast<const float4*>(gam)[tid];
  float4 bv = reinterpret_cast<const float4*>(bet)[tid];
  ushort4 o;
  o.x = f2bf((v0 - mu) * rs * gv.x + bv.x);
  o.y = f2bf((v1 - mu) * rs * gv.y + bv.y);
  o.z = f2bf((v2 - mu) * rs * gv.z + bv.z);
  o.w = f2bf((v3 - mu) * rs * gv.w + bv.w);
  reinterpret_cast<ushort4*>(h + row * 1024)[tid] = o;
}

// ---------------- causal depthwise conv (K=4) + SiLU, vectorized 8 d/thread ----------------
__global__ __launch_bounds__(256)
void k_conv(const unsigned short* __restrict__ xh, const float* __restrict__ cw,
            const float* __restrict__ cb, unsigned short* __restrict__ xc) {
  size_t row = blockIdx.x;                  // 0..8191 = b*L + t
  int t = (int)(row & 2047);
  size_t rowb = row - t;
  int d = threadIdx.x * 8;                  // 8 channels per thread
  float acc[8];
  {
    float4 c0 = *reinterpret_cast<const float4*>(cb + d);
    float4 c1 = *reinterpret_cast<const float4*>(cb + d + 4);
    acc[0] = c0.x; acc[1] = c0.y; acc[2] = c0.z; acc[3] = c0.w;
    acc[4] = c1.x; acc[5] = c1.y; acc[6] = c1.z; acc[7] = c1.w;
  }
  float wv[8][4];
#pragma unroll
  for (int j = 0; j < 8; ++j) {
    float4 cj = *reinterpret_cast<const float4*>(cw + (size_t)(d + j) * 4);
    wv[j][0] = cj.x; wv[j][1] = cj.y; wv[j][2] = cj.z; wv[j][3] = cj.w;
  }
#pragma unroll
  for (int k = 0; k < 4; ++k) {
    int tt = t - 3 + k;
    if (tt >= 0) {
      ushort4 va = reinterpret_cast<const ushort4*>(xh + (rowb + tt) * 2048 + d)[0];
      ushort4 vb = reinterpret_cast<const ushort4*>(xh + (rowb + tt) * 2048 + d)[1];
      unsigned short e[8] = {va.x, va.y, va.z, va.w, vb.x, vb.y, vb.z, vb.w};
#pragma unroll
      for (int j = 0; j < 8; ++j) acc[j] += wv[j][k] * bf2f(e[j]);
    }
  }
  ushort4 o0, o1;
#pragma unroll
  for (int j = 0; j < 8; ++j) {
    float sg = 1.f / (1.f + __expf(-acc[j]));
    unsigned short r = f2bf(acc[j] * sg);
    if (j < 4) (&o0.x)[j] = r; else (&o1.x)[j - 4] = r;
  }
  reinterpret_cast<ushort4*>(xc + row * 2048 + d)[0] = o0;
  reinterpret_cast<ushort4*>(xc + row * 2048 + d)[1] = o1;
}

// ---------------- chunked selective scan: 64 chunks x 32 steps ----------------
// Depth-1 software prefetch of next step's dt/xc/z (loads issue under current step's FMAs).
template <bool FINAL>
__global__ __launch_bounds__(256)
void k_scan(const unsigned short* __restrict__ dt, const unsigned short* __restrict__ xc,
            const unsigned short* __restrict__ dbl, const float* __restrict__ A_log,
            float* __restrict__ S, float* __restrict__ SD,
            const float* __restrict__ Hin, const float* __restrict__ Dp,
            const unsigned short* __restrict__ z, unsigned short* __restrict__ yg) {
  int d = blockIdx.x * 256 + threadIdx.x;
  int b = blockIdx.y, c = blockIdx.z;        // c in 0..63
  int t0 = c * 32;
  size_t hoff = (((size_t)c * 4 + b) * 2048 + d) * 16;
  float An[16], h[16];
  bool fast = true;
#pragma unroll
  for (int n = 0; n < 16; ++n) {
    An[n] = -__expf(A_log[((size_t)d << 4) + n]);
    fast = fast && (__builtin_fabsf(An[n] + (float)(n + 1)) < 1e-4f);
    h[n] = FINAL ? Hin[hoff + n] : 0.f;
  }
  float Dv = FINAL ? Dp[d] : 0.f;
  float dts = 0.f;
  __shared__ float sBC[32][32];
  if (threadIdx.x < 128) {
    int s = threadIdx.x >> 2, j8 = (threadIdx.x & 3) * 8;
    size_t rowg = (size_t)b * 2048 + t0 + s;
    uint4 raw = *reinterpret_cast<const uint4*>(dbl + rowg * 128 + 64 + j8);
    unsigned rr4[4] = {raw.x, raw.y, raw.z, raw.w};
#pragma unroll
    for (int q = 0; q < 4; ++q) {
      sBC[s][j8 + 2 * q]     = bf2f((unsigned short)(rr4[q] & 0xffffu));
      sBC[s][j8 + 2 * q + 1] = bf2f((unsigned short)(rr4[q] >> 16));
    }
  }
  __syncthreads();

  const size_t rbase = ((size_t)b * 2048 + t0) * 2048 + d;
  if (fast) {
    float dtv = bf2f(dt[rbase]);
    float uv  = bf2f(xc[rbase]);
    float zv  = FINAL ? bf2f(z[rbase]) : 0.f;
    for (int si = 0; si < 32; ++si) {
      // prefetch next step (clamped at tail) — issues under this step's FMA chain
      size_t rnext = rbase + (size_t)(si + 1 < 32 ? si + 1 : 31) * 2048;
      float dtv_n = bf2f(dt[rnext]);
      float uv_n  = bf2f(xc[rnext]);
      float zv_n  = FINAL ? bf2f(z[rnext]) : 0.f;
      float dtu = dtv * uv;
      float y = 0.f;
      if constexpr (!FINAL) dts += dtv;
      float e1 = __expf(-dtv);
      float e2 = e1 * e1;
      float e3 = e2 * e1, e4 = e2 * e2;
      float e8 = e4 * e4, e12 = e8 * e4;
      float base[4] = {e1, e2, e3, e4};
      float mul[4] = {1.f, e4, e8, e12};
#pragma unroll
      for (int n = 0; n < 16; ++n) {
        float a = base[n & 3] * mul[n >> 2];
        h[n] = a * h[n] + dtu * sBC[si][n];
        if constexpr (FINAL) y += h[n] * sBC[si][16 + n];
      }
      if constexpr (FINAL) {
        float sig = 1.f / (1.f + __expf(-zv));
        yg[rbase + (size_t)si * 2048] = f2bf((y + Dv * uv) * (zv * sig));
      }
      dtv = dtv_n; uv = uv_n; zv = zv_n;
    }
  } else {
    for (int si = 0; si < 32; ++si) {
      size_t rr = rbase + (size_t)si * 2048;
      float dtv = bf2f(dt[rr]);
      float uv = bf2f(xc[rr]);
      float dtu = dtv * uv;
      float y = 0.f;
      if constexpr (!FINAL) dts += dtv;
#pragma unroll
      for (int n = 0; n < 16; ++n) {
        float a = __expf(dtv * An[n]);
        h[n] = a * h[n] + dtu * sBC[si][n];
        if constexpr (FINAL) y += h[n] * sBC[si][16 + n];
      }
      if constexpr (FINAL) {
        float zv = bf2f(z[rr]);
        float sig = 1.f / (1.f + __expf(-zv));
        yg[rr] = f2bf((y + Dv * uv) * (zv * sig));
      }
    }
  }
  if constexpr (!FINAL) {
#pragma unroll
    for (int n = 0; n < 16; ++n) S[hoff + n] = h[n];
    SD[((size_t)c * 4 + b) * 2048 + d] = dts;
  }
}

// ---------------- chunk combine, in place: S[c] <- state ENTERING chunk c ----------------
__global__ __launch_bounds__(256)
void k_scanB(float* __restrict__ S, const float* __restrict__ SD,
             const float* __restrict__ A_log) {
  int id = blockIdx.x * 256 + threadIdx.x;   // B*DI*N = 131072
  int n = id & 15, d = (id >> 4) & 2047, b = id >> 15;
  float An = -__expf(A_log[((size_t)d << 4) + n]);
  float h = 0.f;
  for (int c = 0; c < 64; ++c) {
    size_t sdo = ((size_t)c * 4 + b) * 2048 + d;
    size_t o = sdo * 16 + n;
    float s = S[o];
    float p = __expf(An * SD[sdo]);
    S[o] = h;                 // Hin in place
    h = s + p * h;
  }
}

extern "C" void kernel_launch(void* const* d_in, const int* in_sizes, int n_in,
                              void* d_out, int out_size, void* d_ws, size_t ws_size,
                              hipStream_t stream) {
  const float* x       = (const float*)d_in[0];
  const float* ev      = (const float*)d_in[1];
  const float* W_in    = (const float*)d_in[2];
  const float* b_in    = (const float*)d_in[3];
  const float* ln_g    = (const float*)d_in[4];
  const float* ln_b    = (const float*)d_in[5];
  const float* in_proj = (const float*)d_in[6];
  const float* conv_w  = (const float*)d_in[7];
  const float* conv_b  = (const float*)d_in[8];
  const float* x_proj  = (const float*)d_in[9];
  const float* dt_proj = (const float*)d_in[10];
  const float* dt_b    = (const float*)d_in[11];
  const float* A_log   = (const float*)d_in[12];
  const float* D_par   = (const float*)d_in[13];
  const float* out_w   = (const float*)d_in[14];
  float* out = (float*)d_out;

  char* ws = (char*)d_ws;
  size_t off = 0;
  auto alloc = [&](size_t bytes) {
    char* p = ws + off;
    off = (off + bytes + 255) & ~(size_t)255;
    return p;
  };
  unsigned short* augb  = (unsigned short*)alloc(8192ull * 1024 * 2);  // residual, bf16
  unsigned short* dtfb  = (unsigned short*)alloc(8192ull * 2048 * 2);  // dt (softplus), bf16
  unsigned short* Aaug  = (unsigned short*)alloc(8192ull * 1152 * 2);  // K padded to 1152
  unsigned short* WinT  = (unsigned short*)alloc(1024ull * 1152 * 2);
  unsigned short* ipT   = (unsigned short*)alloc(4096ull * 1024 * 2);
  unsigned short* xpT   = (unsigned short*)alloc(128ull * 2048 * 2);
  unsigned short* dpT   = (unsigned short*)alloc(2048ull * 64 * 2);
  unsigned short* opT   = (unsigned short*)alloc(1024ull * 2048 * 2);
  unsigned short* xh    = (unsigned short*)alloc(8192ull * 2048 * 2);
  unsigned short* zb    = (unsigned short*)alloc(8192ull * 2048 * 2);
  unsigned short* xcb   = (unsigned short*)alloc(8192ull * 2048 * 2);
  unsigned short* dbl   = (unsigned short*)alloc(8192ull * 128 * 2);
  float* Pd = (float*)alloc(2ull * 8192 * 128 * 4);   // dbl split-K partials (fp32)
  float* Sb = (float*)alloc(64ull * 4 * 2048 * 16 * 4);
  float* SD = (float*)alloc(64ull * 4 * 2048 * 4);
  unsigned short* hb = Aaug;  // LN output aliases Aaug (Aaug dead after aug-gemm)
  unsigned short* yg = xh;    // gated y aliases xh (xh dead after k_conv)

  // fused prep: concat (16384) + WinT (1152) + ipT (4096) + xpT (256) + dpT (128) + opT (2048)
  k_prep<<<dim3(24064), 256, 0, stream>>>(x, ev, Aaug, W_in, WinT, in_proj, ipT,
                                          x_proj, xpT, dt_proj, dpT, out_w, opT);

  // aug = bf16([x|ev] @ W_in + b_in)   (residual); K 1088 padded to 1152 (NT=18)
  k_gemm8<128, 0><<<dim3(8, 32), 512, 0, stream>>>(Aaug, WinT, 1024, 18, 1152, 1152,
                                                   nullptr, augb, nullptr, b_in, nullptr);
  k_ln<<<dim3(8192), 256, 0, stream>>>(augb, ln_g, ln_b, hb);
  // xz = h @ in_proj -> xh | z   — 2-phase 128² double-buffer, 2 blocks/CU
  k_gemm2<1><<<dim3(32, 64), 256, 0, stream>>>(hb, ipT, 4096, 1024, 1024, 1024, xh, zb);
  k_conv<<<dim3(8192), 256, 0, stream>>>(xh, conv_w, conv_b, xcb);
  // dbl = xc @ x_proj (N padded 96->128), split-K=2 partials then combine
  k_gemm<6><<<dim3(2, 64), 256, 0, stream>>>(xcb, xpT, 128, 1024, 2048, 2048,
                                             nullptr, nullptr, Pd);
  k_comb<<<dim3(1024), 256, 0, stream>>>(Pd, dbl);
  // dt = softplus(dbl[:, :64] @ dt_proj + b) -> bf16
  k_gemm<3><<<dim3(16, 64), 256, 0, stream>>>(dbl, dpT, 2048, 64, 128, 64,
                                              dtfb, dt_b, nullptr);
  // chunked scan: A (local), B (combine, in place), C (final + gating)
  k_scan<false><<<dim3(8, 4, 64), 256, 0, stream>>>(dtfb, xcb, dbl, A_log, Sb, SD,
                                                    nullptr, nullptr, nullptr, nullptr);
  k_scanB<<<dim3(512), 256, 0, stream>>>(Sb, SD, A_log);
  k_scan<true><<<dim3(8, 4, 64), 256, 0, stream>>>(dtfb, xcb, dbl, A_log, nullptr, nullptr,
                                                   Sb, D_par, zb, yg);
  // out = bf16resid + yg @ out_proj   (NT=32)
  k_gemm8<128, 4><<<dim3(8, 32), 512, 0, stream>>>(yg, opT, 1024, 32, 2048, 2048,
                                                   out, nullptr, nullptr, nullptr, augb);
}

// Round 15
// 373.088 us; speedup vs baseline: 1.0337x; 1.0337x over previous
//
#include <hip/hip_runtime.h>
#include <cstdint>
#include <cstddef>

#define DEV __device__ __forceinline__

typedef __bf16 bf16x8 __attribute__((ext_vector_type(8)));
typedef float f32x4 __attribute__((ext_vector_type(4)));

DEV unsigned short f2bf(float f) {
  unsigned u = __builtin_bit_cast(unsigned, f);
  u += 0x7fffu + ((u >> 16) & 1u);   // RNE
  return (unsigned short)(u >> 16);
}
DEV float bf2f(unsigned short h) {
  return __builtin_bit_cast(float, (unsigned)h << 16);
}

// =====================================================================================
// Fused prep: concat [x|event]->Aaug[8192x1152]  +  5 weight transposes.
// =====================================================================================
__global__ __launch_bounds__(256)
void k_prep(const float* __restrict__ x, const float* __restrict__ ev,
            unsigned short* __restrict__ Aaug,
            const float* __restrict__ W_in, unsigned short* __restrict__ WinT,
            const float* __restrict__ ipW, unsigned short* __restrict__ ipT,
            const float* __restrict__ xpW, unsigned short* __restrict__ xpT,
            const float* __restrict__ dpW, unsigned short* __restrict__ dpT,
            const float* __restrict__ opW, unsigned short* __restrict__ opT) {
  int tid = threadIdx.x;
  int idx = blockIdx.x;
  // R0: concat, 16384 blocks
  if (idx < 16384) {
    int col4 = (idx & 1) * 256 + tid;
    if (col4 >= 288) return;
    size_t row = idx >> 1;
    float4 v = make_float4(0.f, 0.f, 0.f, 0.f);
    if (col4 < 256)      v = reinterpret_cast<const float4*>(x + row * 1024)[col4];
    else if (col4 < 272) v = reinterpret_cast<const float4*>(ev + row * 64)[col4 - 256];
    ushort4 o; o.x = f2bf(v.x); o.y = f2bf(v.y); o.z = f2bf(v.z); o.w = f2bf(v.w);
    reinterpret_cast<ushort4*>(Aaug + row * 1152)[col4] = o;
    return;
  }
  idx -= 16384;
  const float* in; unsigned short* out; int R, C, Rout, Cout, gx;
  if (idx < 1152)      { in = W_in; out = WinT; R = 1088; C = 1024; Rout = 1152; Cout = 1024; gx = 32; }
  else if ((idx -= 1152) < 4096) { in = ipW; out = ipT; R = 1024; C = 4096; Rout = 1024; Cout = 4096; gx = 128; }
  else if ((idx -= 4096) < 256)  { in = xpW; out = xpT; R = 2048; C = 96;   Rout = 2048; Cout = 128;  gx = 4;   }
  else if ((idx -= 256) < 128)   { in = dpW; out = dpT; R = 64;   C = 2048; Rout = 64;   Cout = 2048; gx = 64;  }
  else                 { idx -= 128; in = opW; out = opT; R = 2048; C = 1024; Rout = 2048; Cout = 1024; gx = 32; }
  int cx = idx % gx, ry = idx / gx;
  __shared__ float tile[32][33];
  int c0 = cx * 32, r0 = ry * 32;
  int tx = tid & 31, ty = tid >> 5;   // 32 x 8
#pragma unroll
  for (int i = 0; i < 4; ++i) {
    int r = r0 + ty + i * 8, c = c0 + tx;
    tile[ty + i * 8][tx] = (r < R && c < C) ? in[(size_t)r * C + c] : 0.f;
  }
  __syncthreads();
#pragma unroll
  for (int i = 0; i < 4; ++i) {
    int c = c0 + ty + i * 8, r = r0 + tx;
    if (c < Cout && r < Rout) out[(size_t)c * Rout + r] = f2bf(tile[tx][ty + i * 8]);
  }
}

// =====================================================================================
// 4-WINDOW 256xBN MFMA GEMM (r8 schedule, frozen).
// EPI 0: outB1 = bf16(acc + bias[col]);  EPI 1: halves -> outB1/outB2 bf16;
// EPI 4: outF = bf16resid + acc (fp32 out).
// =====================================================================================
template <int BN, int EPI>
__global__ __launch_bounds__(512, 1)
void k_gemm8(const unsigned short* __restrict__ A, const unsigned short* __restrict__ Bt,
             int N, int NT, int lda, int ldb,
             float* __restrict__ outF, unsigned short* __restrict__ outB1,
             unsigned short* __restrict__ outB2,
             const float* __restrict__ bias, const unsigned short* __restrict__ residB) {
  static_assert(BN == 128 || BN == 256, "");
  constexpr int NF = BN / 64;
  constexpr int NHF = NF / 2;
  constexpr int BLOADS = BN / 128;
  constexpr int ATILE = 256 * 64;
  constexpr int BTILE = BN * 64;
  constexpr int BUFSZ = ATILE + BTILE;
  __shared__ unsigned short lds[2 * BUFSZ];

  const int tid = threadIdx.x;
  const int lane = tid & 63, w = tid >> 6;
  const int wm = w >> 2, wn = w & 3;
  const int frow = lane & 15, fk = lane >> 4;

  const int nbx = gridDim.x;
  const int nwg = nbx * gridDim.y;
  const int orig = blockIdx.y * nbx + blockIdx.x;
  const int swz = (orig & 7) * (nwg >> 3) + (orig >> 3);
  const int brow = swz / nbx, bcol = swz % nbx;
  const size_t row0 = (size_t)brow * 256, col0 = (size_t)bcol * BN;

  f32x4 acc[8][NF];
#pragma unroll
  for (int i = 0; i < 8; ++i)
#pragma unroll
    for (int j = 0; j < NF; ++j) acc[i][j] = f32x4{0.f, 0.f, 0.f, 0.f};

  bf16x8 afr[4][2], bq0[NHF][2], bq1[NHF][2];

  const int srow = tid >> 3;
  const int g8 = ((tid & 7) ^ (srow & 7)) * 8;
  const size_t offA_h0l0 = (row0 + 0 * 128 + 0 * 64 + srow) * (size_t)lda + g8;
  const size_t offA_h0l1 = (row0 + 1 * 128 + 0 * 64 + srow) * (size_t)lda + g8;
  const size_t offA_h1l0 = (row0 + 0 * 128 + 1 * 64 + srow) * (size_t)lda + g8;
  const size_t offA_h1l1 = (row0 + 1 * 128 + 1 * 64 + srow) * (size_t)lda + g8;
  const size_t offB_h0l0 = (col0 + 0 * (BN / 2) + 0 * 64 + srow) * (size_t)ldb + g8;
  const size_t offB_h1l0 = (col0 + 1 * (BN / 2) + 0 * 64 + srow) * (size_t)ldb + g8;
  const size_t offB_h0l1 = (BLOADS == 2) ? ((col0 + 0 * (BN / 2) + 1 * 64 + srow) * (size_t)ldb + g8) : 0;
  const size_t offB_h1l1 = (BLOADS == 2) ? ((col0 + 1 * (BN / 2) + 1 * 64 + srow) * (size_t)ldb + g8) : 0;

  char* ldsb = reinterpret_cast<char*>(lds);
  const int fr7 = frow & 7;
  const int slot0 = (fk ^ fr7) * 16;
  const int slot1 = ((4 + fk) ^ fr7) * 16;
  const int abase0 = (wm * 128 + frow) * 128 + slot0;
  const int abase1 = (wm * 128 + frow) * 128 + slot1;
  const int bbase0 = (wn * (BN / 4) + frow) * 128 + slot0 + ATILE * 2;
  const int bbase1 = (wn * (BN / 4) + frow) * 128 + slot1 + ATILE * 2;

  auto stageA = [&](int p, int tau, int half) {
    const size_t kadd = (size_t)tau * 64;
    const unsigned short* s0 = A + (half ? offA_h1l0 : offA_h0l0) + kadd;
    const unsigned short* s1 = A + (half ? offA_h1l1 : offA_h0l1) + kadd;
    unsigned short* dst = lds + p * BUFSZ + half * 4096 + w * 512;
    __builtin_amdgcn_global_load_lds(s0, dst, 16, 0, 0);
    __builtin_amdgcn_global_load_lds(s1, dst + 8192, 16, 0, 0);
  };
  auto stageB = [&](int p, int tau, int half) {
    const size_t kadd = (size_t)tau * 64;
    unsigned short* dst = lds + p * BUFSZ + ATILE + half * (BTILE / 2) + w * 512;
    const unsigned short* s0 = Bt + (half ? offB_h1l0 : offB_h0l0) + kadd;
    __builtin_amdgcn_global_load_lds(s0, dst, 16, 0, 0);
    if constexpr (BLOADS == 2) {
      const unsigned short* s1 = Bt + (half ? offB_h1l1 : offB_h0l1) + kadd;
      __builtin_amdgcn_global_load_lds(s1, dst + 4096, 16, 0, 0);
    }
  };
  auto ldA = [&](int p, int mh) {
    const int pb = p * (BUFSZ * 2);
#pragma unroll
    for (int mi = 0; mi < 4; ++mi) {
      const int off = pb + (mh * 64 + mi * 16) * 128;
      afr[mi][0] = *reinterpret_cast<const bf16x8*>(ldsb + abase0 + off);
      afr[mi][1] = *reinterpret_cast<const bf16x8*>(ldsb + abase1 + off);
    }
  };
  auto ldB = [&](int p, int nh, bf16x8 (&bq)[NHF][2]) {
    const int pb = p * (BUFSZ * 2);
#pragma unroll
    for (int ni = 0; ni < NHF; ++ni) {
      const int off = pb + (nh * (BN / 8) + ni * 16) * 128;
      bq[ni][0] = *reinterpret_cast<const bf16x8*>(ldsb + bbase0 + off);
      bq[ni][1] = *reinterpret_cast<const bf16x8*>(ldsb + bbase1 + off);
    }
  };

#define MMAQ(MH, NH, BQ)                                                          \
  do {                                                                            \
    _Pragma("unroll") for (int mi = 0; mi < 4; ++mi)                              \
        _Pragma("unroll") for (int ni = 0; ni < NHF; ++ni)                        \
            _Pragma("unroll") for (int kb = 0; kb < 2; ++kb)                      \
                acc[(MH)*4 + mi][(NH)*NHF + ni] =                                 \
                    __builtin_amdgcn_mfma_f32_16x16x32_bf16(                      \
                        afr[mi][kb], BQ[ni][kb], acc[(MH)*4 + mi][(NH)*NHF + ni], \
                        0, 0, 0);                                                 \
  } while (0)

#define PRIO1 __builtin_amdgcn_s_setprio(1)
#define PRIO0 __builtin_amdgcn_s_setprio(0)
#define BARC  __builtin_amdgcn_s_barrier()
#define SBAR  __builtin_amdgcn_sched_barrier(0)
#define VMCNT_WAIT                                                     \
  do {                                                                 \
    if constexpr (BN == 256)                                           \
      asm volatile("s_waitcnt vmcnt(6)" ::: "memory");                 \
    else                                                               \
      asm volatile("s_waitcnt vmcnt(4)" ::: "memory");                 \
  } while (0)

  stageA(0, 0, 0); stageB(0, 0, 0); stageB(0, 0, 1); stageA(0, 0, 1);
  SBAR;
  stageA(1, 1, 0); stageB(1, 1, 0); stageB(1, 1, 1);
  VMCNT_WAIT;
  BARC; SBAR;

  const int niter = NT >> 1;
  for (int it = 0; it < niter; ++it) {
    int t = 2 * it;
    int t1s = t + 1;
    int t2s = (t + 2 < NT) ? t + 2 : NT - 1;
    int t3s = (t + 3 < NT) ? t + 3 : NT - 1;
    // alpha (tile t, buf0)
    ldA(0, 0); ldB(0, 0, bq0); ldB(0, 1, bq1);
    stageA(1, t1s, 1);
    BARC; PRIO1; MMAQ(0, 0, bq0); MMAQ(0, 1, bq1); PRIO0; BARC;
    // beta (tile t, buf0)
    ldA(0, 1);
    stageA(0, t2s, 0); stageB(0, t2s, 0); stageB(0, t2s, 1);
    VMCNT_WAIT;
    BARC; PRIO1; MMAQ(1, 1, bq1); MMAQ(1, 0, bq0); PRIO0; BARC;
    // gamma (tile t+1, buf1)
    ldA(1, 0); ldB(1, 0, bq0); ldB(1, 1, bq1);
    stageA(0, t2s, 1);
    BARC; PRIO1; MMAQ(0, 0, bq0); MMAQ(0, 1, bq1); PRIO0; BARC;
    // delta (tile t+1, buf1)
    ldA(1, 1);
    stageA(1, t3s, 0); stageB(1, t3s, 0); stageB(1, t3s, 1);
    VMCNT_WAIT;
    BARC; PRIO1; MMAQ(1, 1, bq1); MMAQ(1, 0, bq0); PRIO0; BARC;
  }

#pragma unroll
  for (int q = 0; q < 8; ++q) {
#pragma unroll
    for (int j = 0; j < NF; ++j) {
#pragma unroll
      for (int r = 0; r < 4; ++r) {
        size_t row = row0 + wm * 128 + q * 16 + fk * 4 + r;
        size_t col = col0 + wn * (BN / 4) + j * 16 + frow;
        float v = acc[q][j][r];
        if constexpr (EPI == 0) {
          outB1[row * N + col] = f2bf(v + bias[col]);
        } else if constexpr (EPI == 1) {
          int hn = N >> 1;
          if ((int)col < hn) outB1[row * hn + col] = f2bf(v);
          else               outB2[row * hn + (col - hn)] = f2bf(v);
        } else {
          outF[row * N + col] = bf2f(residB[row * N + col]) + v;
        }
      }
    }
  }
#undef MMAQ
#undef PRIO1
#undef PRIO0
#undef BARC
#undef SBAR
#undef VMCNT_WAIT
}

// ---------------- 128x128 MFMA GEMM (m97 structure) for the small GEMMs ----------------
// EPI 3: outB1 = bf16(softplus(acc + bias[col]))  (dt)
// EPI 6: split-K partial: outF[kslice] (fp32, kslice = bcol; col0 forced 0)
template <int EPI>
__global__ __launch_bounds__(256)
void k_gemm(const unsigned short* __restrict__ A, const unsigned short* __restrict__ Bt,
            int N, int K, int lda, int ldb,
            unsigned short* __restrict__ outB1, const float* __restrict__ bias,
            float* __restrict__ outF) {
  __shared__ alignas(16) unsigned short sA[128 * 64];
  __shared__ alignas(16) unsigned short sB[128 * 64];
  int tid = threadIdx.x;
  int lane = tid & 63, w = tid >> 6;
  int nbx = gridDim.x;
  int nwg = nbx * gridDim.y;
  int orig = blockIdx.y * nbx + blockIdx.x;
  int swz = (orig & 7) * (nwg >> 3) + (orig >> 3);
  int brow = swz / nbx, bcol = swz % nbx;
  size_t row0 = (size_t)brow * 128, col0 = (size_t)bcol * 128;
  int ks = 0;
  if constexpr (EPI == 6) { ks = bcol; col0 = 0; }
  const size_t kbase = (size_t)ks * 1024;

  int lrow_s = tid >> 3;
  int g_s = tid & 7;
  int wrow = (w >> 1) * 64, wcol = (w & 1) * 64;
  int frow = lane & 15, fk = lane >> 4;
  f32x4 acc[4][4] = {};

  for (int kt = 0; kt < K; kt += 64) {
    __syncthreads();
#pragma unroll
    for (int r = 0; r < 4; ++r) {
      int lr = r * 32 + lrow_s;
      int gs = g_s ^ (lr & 7);
      const unsigned short* srcA = A + (size_t)(row0 + lr) * lda + kbase + kt + gs * 8;
      const unsigned short* srcB = Bt + (size_t)(col0 + lr) * ldb + kbase + kt + gs * 8;
      unsigned short* dstA = sA + (r * 32 + w * 8) * 64;
      unsigned short* dstB = sB + (r * 32 + w * 8) * 64;
      __builtin_amdgcn_global_load_lds(srcA, dstA, 16, 0, 0);
      __builtin_amdgcn_global_load_lds(srcB, dstB, 16, 0, 0);
    }
    __syncthreads();
#pragma unroll
    for (int kw = 0; kw < 2; ++kw) {
      bf16x8 af[4], bfr[4];
      int gk = kw * 4 + fk;
#pragma unroll
      for (int mi = 0; mi < 4; ++mi) {
        int rr = wrow + mi * 16 + frow;
        af[mi] = *reinterpret_cast<const bf16x8*>(sA + rr * 64 + ((gk ^ (rr & 7)) * 8));
      }
#pragma unroll
      for (int ni = 0; ni < 4; ++ni) {
        int rr = wcol + ni * 16 + frow;
        bfr[ni] = *reinterpret_cast<const bf16x8*>(sB + rr * 64 + ((gk ^ (rr & 7)) * 8));
      }
#pragma unroll
      for (int mi = 0; mi < 4; ++mi)
#pragma unroll
        for (int ni = 0; ni < 4; ++ni)
          acc[mi][ni] = __builtin_amdgcn_mfma_f32_16x16x32_bf16(af[mi], bfr[ni], acc[mi][ni], 0, 0, 0);
    }
  }

#pragma unroll
  for (int mi = 0; mi < 4; ++mi) {
#pragma unroll
    for (int ni = 0; ni < 4; ++ni) {
#pragma unroll
      for (int r = 0; r < 4; ++r) {
        size_t row = row0 + wrow + mi * 16 + fk * 4 + r;
        size_t col = col0 + wcol + ni * 16 + frow;
        float v = acc[mi][ni][r];
        if constexpr (EPI == 6) {
          outF[(size_t)ks * (8192ull * 128) + row * 128 + col] = v;
        } else {
          float xx = v + bias[col];
          float sp = (xx > 15.f) ? xx : __logf(1.f + __expf(xx));
          outB1[row * N + col] = f2bf(sp);
        }
      }
    }
  }
}

// ---------------- combine split-K partials -> bf16 dbl ----------------
__global__ __launch_bounds__(256)
void k_comb(const float* __restrict__ P, unsigned short* __restrict__ dbl) {
  size_t i4 = (size_t)blockIdx.x * 256 + threadIdx.x;   // float4 index, 262144 total
  float4 a = reinterpret_cast<const float4*>(P)[i4];
  float4 b = reinterpret_cast<const float4*>(P + 8192ull * 128)[i4];
  ushort4 o;
  o.x = f2bf(a.x + b.x); o.y = f2bf(a.y + b.y);
  o.z = f2bf(a.z + b.z); o.w = f2bf(a.w + b.w);
  reinterpret_cast<ushort4*>(dbl)[i4] = o;
}

// ---------------- LayerNorm over D=1024, bf16 in -> bf16 out ----------------
__global__ __launch_bounds__(256)
void k_ln(const unsigned short* __restrict__ aug, const float* __restrict__ gam,
          const float* __restrict__ bet, unsigned short* __restrict__ h) {
  int tid = threadIdx.x;
  size_t row = blockIdx.x;
  ushort4 raw = reinterpret_cast<const ushort4*>(aug + row * 1024)[tid];
  float v0 = bf2f(raw.x), v1 = bf2f(raw.y), v2 = bf2f(raw.z), v3 = bf2f(raw.w);
  float s = v0 + v1 + v2 + v3;
  float ss = v0 * v0 + v1 * v1 + v2 * v2 + v3 * v3;
#pragma unroll
  for (int m = 32; m >= 1; m >>= 1) {
    s += __shfl_xor(s, m, 64);
    ss += __shfl_xor(ss, m, 64);
  }
  __shared__ float rb[8];
  if ((tid & 63) == 0) { rb[tid >> 6] = s; rb[4 + (tid >> 6)] = ss; }
  __syncthreads();
  float ts = rb[0] + rb[1] + rb[2] + rb[3];
  float tss = rb[4] + rb[5] + rb[6] + rb[7];
  float mu = ts * (1.f / 1024.f);
  float var = tss * (1.f / 1024.f) - mu * mu;
  float rs = rsqrtf(var + 1e-5f);
  float4 gv = reinterpret_cast<const float4*>(gam)[tid];
  float4 bv = reinterpret_cast<const float4*>(bet)[tid];
  ushort4 o;
  o.x = f2bf((v0 - mu) * rs * gv.x + bv.x);
  o.y = f2bf((v1 - mu) * rs * gv.y + bv.y);
  o.z = f2bf((v2 - mu) * rs * gv.z + bv.z);
  o.w = f2bf((v3 - mu) * rs * gv.w + bv.w);
  reinterpret_cast<ushort4*>(h + row * 1024)[tid] = o;
}

// ---------------- causal depthwise conv (K=4) + SiLU, vectorized 8 d/thread ----------------
__global__ __launch_bounds__(256)
void k_conv(const unsigned short* __restrict__ xh, const float* __restrict__ cw,
            const float* __restrict__ cb, unsigned short* __restrict__ xc) {
  size_t row = blockIdx.x;                  // 0..8191 = b*L + t
  int t = (int)(row & 2047);
  size_t rowb = row - t;
  int d = threadIdx.x * 8;                  // 8 channels per thread
  float acc[8];
  {
    float4 c0 = *reinterpret_cast<const float4*>(cb + d);
    float4 c1 = *reinterpret_cast<const float4*>(cb + d + 4);
    acc[0] = c0.x; acc[1] = c0.y; acc[2] = c0.z; acc[3] = c0.w;
    acc[4] = c1.x; acc[5] = c1.y; acc[6] = c1.z; acc[7] = c1.w;
  }
  float wv[8][4];
#pragma unroll
  for (int j = 0; j < 8; ++j) {
    float4 cj = *reinterpret_cast<const float4*>(cw + (size_t)(d + j) * 4);
    wv[j][0] = cj.x; wv[j][1] = cj.y; wv[j][2] = cj.z; wv[j][3] = cj.w;
  }
#pragma unroll
  for (int k = 0; k < 4; ++k) {
    int tt = t - 3 + k;
    if (tt >= 0) {
      ushort4 va = reinterpret_cast<const ushort4*>(xh + (rowb + tt) * 2048 + d)[0];
      ushort4 vb = reinterpret_cast<const ushort4*>(xh + (rowb + tt) * 2048 + d)[1];
      unsigned short e[8] = {va.x, va.y, va.z, va.w, vb.x, vb.y, vb.z, vb.w};
#pragma unroll
      for (int j = 0; j < 8; ++j) acc[j] += wv[j][k] * bf2f(e[j]);
    }
  }
  ushort4 o0, o1;
#pragma unroll
  for (int j = 0; j < 8; ++j) {
    float sg = 1.f / (1.f + __expf(-acc[j]));
    unsigned short r = f2bf(acc[j] * sg);
    if (j < 4) (&o0.x)[j] = r; else (&o1.x)[j - 4] = r;
  }
  reinterpret_cast<ushort4*>(xc + row * 2048 + d)[0] = o0;
  reinterpret_cast<ushort4*>(xc + row * 2048 + d)[1] = o1;
}

// ---------------- chunked selective scan: 64 chunks x 32 steps ----------------
// Depth-1 software prefetch of next step's dt/xc/z (loads issue under current step's FMAs).
template <bool FINAL>
__global__ __launch_bounds__(256)
void k_scan(const unsigned short* __restrict__ dt, const unsigned short* __restrict__ xc,
            const unsigned short* __restrict__ dbl, const float* __restrict__ A_log,
            float* __restrict__ S, float* __restrict__ SD,
            const float* __restrict__ Hin, const float* __restrict__ Dp,
            const unsigned short* __restrict__ z, unsigned short* __restrict__ yg) {
  int d = blockIdx.x * 256 + threadIdx.x;
  int b = blockIdx.y, c = blockIdx.z;        // c in 0..63
  int t0 = c * 32;
  size_t hoff = (((size_t)c * 4 + b) * 2048 + d) * 16;
  float An[16], h[16];
  bool fast = true;
#pragma unroll
  for (int n = 0; n < 16; ++n) {
    An[n] = -__expf(A_log[((size_t)d << 4) + n]);
    fast = fast && (__builtin_fabsf(An[n] + (float)(n + 1)) < 1e-4f);
    h[n] = FINAL ? Hin[hoff + n] : 0.f;
  }
  float Dv = FINAL ? Dp[d] : 0.f;
  float dts = 0.f;
  __shared__ float sBC[32][32];
  if (threadIdx.x < 128) {
    int s = threadIdx.x >> 2, j8 = (threadIdx.x & 3) * 8;
    size_t rowg = (size_t)b * 2048 + t0 + s;
    uint4 raw = *reinterpret_cast<const uint4*>(dbl + rowg * 128 + 64 + j8);
    unsigned rr4[4] = {raw.x, raw.y, raw.z, raw.w};
#pragma unroll
    for (int q = 0; q < 4; ++q) {
      sBC[s][j8 + 2 * q]     = bf2f((unsigned short)(rr4[q] & 0xffffu));
      sBC[s][j8 + 2 * q + 1] = bf2f((unsigned short)(rr4[q] >> 16));
    }
  }
  __syncthreads();

  const size_t rbase = ((size_t)b * 2048 + t0) * 2048 + d;
  if (fast) {
    float dtv = bf2f(dt[rbase]);
    float uv  = bf2f(xc[rbase]);
    float zv  = FINAL ? bf2f(z[rbase]) : 0.f;
    for (int si = 0; si < 32; ++si) {
      // prefetch next step (clamped at tail) — issues under this step's FMA chain
      size_t rnext = rbase + (size_t)(si + 1 < 32 ? si + 1 : 31) * 2048;
      float dtv_n = bf2f(dt[rnext]);
      float uv_n  = bf2f(xc[rnext]);
      float zv_n  = FINAL ? bf2f(z[rnext]) : 0.f;
      float dtu = dtv * uv;
      float y = 0.f;
      if constexpr (!FINAL) dts += dtv;
      float e1 = __expf(-dtv);
      float e2 = e1 * e1;
      float e3 = e2 * e1, e4 = e2 * e2;
      float e8 = e4 * e4, e12 = e8 * e4;
      float base[4] = {e1, e2, e3, e4};
      float mul[4] = {1.f, e4, e8, e12};
#pragma unroll
      for (int n = 0; n < 16; ++n) {
        float a = base[n & 3] * mul[n >> 2];
        h[n] = a * h[n] + dtu * sBC[si][n];
        if constexpr (FINAL) y += h[n] * sBC[si][16 + n];
      }
      if constexpr (FINAL) {
        float sig = 1.f / (1.f + __expf(-zv));
        yg[rbase + (size_t)si * 2048] = f2bf((y + Dv * uv) * (zv * sig));
      }
      dtv = dtv_n; uv = uv_n; zv = zv_n;
    }
  } else {
    for (int si = 0; si < 32; ++si) {
      size_t rr = rbase + (size_t)si * 2048;
      float dtv = bf2f(dt[rr]);
      float uv = bf2f(xc[rr]);
      float dtu = dtv * uv;
      float y = 0.f;
      if constexpr (!FINAL) dts += dtv;
#pragma unroll
      for (int n = 0; n < 16; ++n) {
        float a = __expf(dtv * An[n]);
        h[n] = a * h[n] + dtu * sBC[si][n];
        if constexpr (FINAL) y += h[n] * sBC[si][16 + n];
      }
      if constexpr (FINAL) {
        float zv = bf2f(z[rr]);
        float sig = 1.f / (1.f + __expf(-zv));
        yg[rr] = f2bf((y + Dv * uv) * (zv * sig));
      }
    }
  }
  if constexpr (!FINAL) {
#pragma unroll
    for (int n = 0; n < 16; ++n) S[hoff + n] = h[n];
    SD[((size_t)c * 4 + b) * 2048 + d] = dts;
  }
}

// ---------------- chunk combine, in place: S[c] <- state ENTERING chunk c ----------------
__global__ __launch_bounds__(256)
void k_scanB(float* __restrict__ S, const float* __restrict__ SD,
             const float* __restrict__ A_log) {
  int id = blockIdx.x * 256 + threadIdx.x;   // B*DI*N = 131072
  int n = id & 15, d = (id >> 4) & 2047, b = id >> 15;
  float An = -__expf(A_log[((size_t)d << 4) + n]);
  float h = 0.f;
  for (int c = 0; c < 64; ++c) {
    size_t sdo = ((size_t)c * 4 + b) * 2048 + d;
    size_t o = sdo * 16 + n;
    float s = S[o];
    float p = __expf(An * SD[sdo]);
    S[o] = h;                 // Hin in place
    h = s + p * h;
  }
}

extern "C" void kernel_launch(void* const* d_in, const int* in_sizes, int n_in,
                              void* d_out, int out_size, void* d_ws, size_t ws_size,
                              hipStream_t stream) {
  const float* x       = (const float*)d_in[0];
  const float* ev      = (const float*)d_in[1];
  const float* W_in    = (const float*)d_in[2];
  const float* b_in    = (const float*)d_in[3];
  const float* ln_g    = (const float*)d_in[4];
  const float* ln_b    = (const float*)d_in[5];
  const float* in_proj = (const float*)d_in[6];
  const float* conv_w  = (const float*)d_in[7];
  const float* conv_b  = (const float*)d_in[8];
  const float* x_proj  = (const float*)d_in[9];
  const float* dt_proj = (const float*)d_in[10];
  const float* dt_b    = (const float*)d_in[11];
  const float* A_log   = (const float*)d_in[12];
  const float* D_par   = (const float*)d_in[13];
  const float* out_w   = (const float*)d_in[14];
  float* out = (float*)d_out;

  char* ws = (char*)d_ws;
  size_t off = 0;
  auto alloc = [&](size_t bytes) {
    char* p = ws + off;
    off = (off + bytes + 255) & ~(size_t)255;
    return p;
  };
  unsigned short* augb  = (unsigned short*)alloc(8192ull * 1024 * 2);  // residual, bf16
  unsigned short* dtfb  = (unsigned short*)alloc(8192ull * 2048 * 2);  // dt (softplus), bf16
  unsigned short* Aaug  = (unsigned short*)alloc(8192ull * 1152 * 2);  // K padded to 1152
  unsigned short* WinT  = (unsigned short*)alloc(1024ull * 1152 * 2);
  unsigned short* ipT   = (unsigned short*)alloc(4096ull * 1024 * 2);
  unsigned short* xpT   = (unsigned short*)alloc(128ull * 2048 * 2);
  unsigned short* dpT   = (unsigned short*)alloc(2048ull * 64 * 2);
  unsigned short* opT   = (unsigned short*)alloc(1024ull * 2048 * 2);
  unsigned short* xh    = (unsigned short*)alloc(8192ull * 2048 * 2);
  unsigned short* zb    = (unsigned short*)alloc(8192ull * 2048 * 2);
  unsigned short* xcb   = (unsigned short*)alloc(8192ull * 2048 * 2);
  unsigned short* dbl   = (unsigned short*)alloc(8192ull * 128 * 2);
  float* Pd = (float*)alloc(2ull * 8192 * 128 * 4);   // dbl split-K partials (fp32)
  float* Sb = (float*)alloc(64ull * 4 * 2048 * 16 * 4);
  float* SD = (float*)alloc(64ull * 4 * 2048 * 4);
  unsigned short* hb = Aaug;  // LN output aliases Aaug (Aaug dead after aug-gemm)
  unsigned short* yg = xh;    // gated y aliases xh (xh dead after k_conv)

  // fused prep: concat (16384) + WinT (1152) + ipT (4096) + xpT (256) + dpT (128) + opT (2048)
  k_prep<<<dim3(24064), 256, 0, stream>>>(x, ev, Aaug, W_in, WinT, in_proj, ipT,
                                          x_proj, xpT, dt_proj, dpT, out_w, opT);

  // aug = bf16([x|ev] @ W_in + b_in)   (residual); K 1088 padded to 1152 (NT=18)
  k_gemm8<128, 0><<<dim3(8, 32), 512, 0, stream>>>(Aaug, WinT, 1024, 18, 1152, 1152,
                                                   nullptr, augb, nullptr, b_in, nullptr);
  k_ln<<<dim3(8192), 256, 0, stream>>>(augb, ln_g, ln_b, hb);
  // xz = h @ in_proj -> xh | z   (NT=16)
  k_gemm8<256, 1><<<dim3(16, 32), 512, 0, stream>>>(hb, ipT, 4096, 16, 1024, 1024,
                                                    nullptr, xh, zb, nullptr, nullptr);
  k_conv<<<dim3(8192), 256, 0, stream>>>(xh, conv_w, conv_b, xcb);
  // dbl = xc @ x_proj (N padded 96->128), split-K=2 partials then combine
  k_gemm<6><<<dim3(2, 64), 256, 0, stream>>>(xcb, xpT, 128, 1024, 2048, 2048,
                                             nullptr, nullptr, Pd);
  k_comb<<<dim3(1024), 256, 0, stream>>>(Pd, dbl);
  // dt = softplus(dbl[:, :64] @ dt_proj + b) -> bf16
  k_gemm<3><<<dim3(16, 64), 256, 0, stream>>>(dbl, dpT, 2048, 64, 128, 64,
                                              dtfb, dt_b, nullptr);
  // chunked scan: A (local), B (combine, in place), C (final + gating)
  k_scan<false><<<dim3(8, 4, 64), 256, 0, stream>>>(dtfb, xcb, dbl, A_log, Sb, SD,
                                                    nullptr, nullptr, nullptr, nullptr);
  k_scanB<<<dim3(512), 256, 0, stream>>>(Sb, SD, A_log);
  k_scan<true><<<dim3(8, 4, 64), 256, 0, stream>>>(dtfb, xcb, dbl, A_log, nullptr, nullptr,
                                                   Sb, D_par, zb, yg);
  // out = bf16resid + yg @ out_proj   (NT=32)
  k_gemm8<128, 4><<<dim3(8, 32), 512, 0, stream>>>(yg, opT, 1024, 32, 2048, 2048,
                                                   out, nullptr, nullptr, nullptr, augb);
}